// Round 2
// baseline (104.627 us; speedup 1.0000x reference)
//
#include <hip/hip_runtime.h>

#define NATOMS 4096
#define TILE   128
#define NTILES (NATOMS / TILE)   // 32
#define KE2F   0.000231f         // f32-rounded, same as np's NEP50 scalar conversion

// Pairs with d2 <= NEAR: replicate np f32 pipeline bitwise (cancellation-amplified).
// Pairs with d2 > NEAR: term magnitude <= ~10; fast-math error ~1e-5 rel -> negligible.
#define NEAR_D2 1.0f

__global__ __launch_bounds__(256) void energy_kernel(
    const float* __restrict__ pos,
    const float* __restrict__ charges,
    const float* __restrict__ bond_coeffs,
    const float* __restrict__ bond_lengths,
    const float* __restrict__ angle_coeffs,
    const float* __restrict__ thetas,
    const float* __restrict__ dihedral_coeffs,
    const float* __restrict__ phis,
    const float* __restrict__ multiplicity,
    const float* __restrict__ lj_E,
    const float* __restrict__ lj_r,
    const int* __restrict__ atom_types,
    const int* __restrict__ lj_types,
    const int* __restrict__ bond_idx,
    const int* __restrict__ angle_idx,
    const int* __restrict__ dihedral_idx,
    float* __restrict__ out)
{
    const int bi  = blockIdx.y;
    const int bj  = blockIdx.x;
    const int tid = threadIdx.x;

    __shared__ float4 sp[TILE];   // x, y, z, charge of j-tile
    __shared__ float  ssq[TILE];  // np-convention f32 squared norm of j
    __shared__ int    st[TILE];   // lj type of j
    __shared__ double red[4];

    double acc = 0.0;

    if (bj >= bi) {
        // ---------------- pairwise LJ + Coulomb tile ----------------
        const int il   = tid & (TILE - 1);
        const int half = tid >> 7;            // 2 threads per i-row, 64 j's each
        const int ig   = bi * TILE + il;
        const int jb   = bj * TILE;

        if (tid < TILE) {
            const int jg = jb + tid;
            const float x = pos[jg*3+0], y = pos[jg*3+1], z = pos[jg*3+2];
            sp[tid]  = make_float4(x, y, z, charges[jg]);
            // np: sum(p*p, -1) -> products rounded, sequential sum ((x2+y2)+z2)
            ssq[tid] = __fadd_rn(__fadd_rn(__fmul_rn(x,x), __fmul_rn(y,y)), __fmul_rn(z,z));
            st[tid]  = lj_types[jg];
        }

        const float xi = pos[ig*3+0], yi = pos[ig*3+1], zi = pos[ig*3+2];
        const float sqi = __fadd_rn(__fadd_rn(__fmul_rn(xi,xi), __fmul_rn(yi,yi)), __fmul_rn(zi,zi));
        const float aqi = __fmul_rn(KE2F, charges[ig]);   // np: KE2 * charges[:,None] first
        const int   ti  = lj_types[ig];
        // i's row of the 4x4 LJ tables (4*E exact: power-of-two scale)
        const float e0 = 4.f*lj_E[ti*4+0], e1 = 4.f*lj_E[ti*4+1],
                    e2 = 4.f*lj_E[ti*4+2], e3 = 4.f*lj_E[ti*4+3];
        const float s0 = lj_r[ti*4+0], s1 = lj_r[ti*4+1],
                    s2 = lj_r[ti*4+2], s3 = lj_r[ti*4+3];

        __syncthreads();

        const int j0 = half * (TILE/2);
        for (int jj = j0; jj < j0 + TILE/2; ++jj) {
            const float4 pj  = sp[jj];
            const float  sqj = ssq[jj];
            const int    tj  = st[jj];
            const int    jg  = jb + jj;
            const bool valid = jg > ig;      // strict upper triangle

            // BLAS sgemm K=3 dot: sequential FMA, ascending k, acc from 0
            const float dot = __fmaf_rn(zi, pj.z,
                              __fmaf_rn(yi, pj.y,
                              __fmaf_rn(xi, pj.x, 0.0f)));
            const float t   = __fadd_rn(sqi, sqj);            // sq[:,None]+sq[None,:]
            const float d2  = __fsub_rn(t, __fmul_rn(2.0f, dot)); // -2*dot (x2 exact)
            const float d2m = fmaxf(d2, 0.0f);
            const float rr2 = __fadd_rn(d2m, 1e-12f);

            const float sig = (tj==0)?s0:(tj==1)?s1:(tj==2)?s2:s3;
            const float e4  = (tj==0)?e0:(tj==1)?e1:(tj==2)?e2:e3;

            if (__builtin_expect(d2m <= NEAR_D2, 0)) {
                // exact np-f32 replication (amplified terms live here)
                if (valid) {
                    const float rf = __fsqrt_rn(rr2);
                    const float qv = __fdiv_rn(sig, rf);
                    const double u  = (double)qv;
                    const double u3 = u*u*u;
                    const float r6 = (float)(u3*u3);          // ~correctly-rounded q**6
                    const float lj = __fsub_rn(__fmul_rn(r6, r6), r6);
                    const float ljt = __fmul_rn(e4, lj);      // (4*eps)*(r12-r6)
                    const float cl  = __fdiv_rn(__fmul_rn(aqi, pj.w), rf);
                    acc += (double)ljt;
                    acc += (double)cl;
                }
            } else {
                // far pair: |term| <= ~10, approximate freely
                const float invr = __builtin_amdgcn_rsqf(rr2);
                const float u  = sig * invr;
                const float u2 = u*u;
                const float u6 = u2*u2*u2;
                const float term = e4 * (u6*u6 - u6) + aqi * pj.w * invr;
                acc += valid ? (double)term : 0.0;
            }
        }
    } else {
        // ---------------- bonded terms on spare lower-tri blocks ----------------
        const int l   = (bi * (bi - 1)) / 2 + bj;   // 0..495
        const int NB  = NATOMS;                     // 4096 bonds
        const int NA  = 2 * NATOMS;                 // 8192 angles
        const int ND  = 3 * NATOMS;                 // 12288 dihedrals
        const int TOT = NB + NA + ND;               // 24576 = 96 blocks exactly
        if (l * 256 >= TOT) return;                 // whole block idle (uniform)
        const int item = l * 256 + tid;

        if (item < NB) {
            const int b1 = bond_idx[item*2+0];
            const int b2 = bond_idx[item*2+1];
            const float dx = pos[b1*3+0] - pos[b2*3+0];
            const float dy = pos[b1*3+1] - pos[b2*3+1];
            const float dz = pos[b1*3+2] - pos[b2*3+2];
            const float d  = sqrtf(dx*dx + dy*dy + dz*dz + 1e-12f);
            const int k    = atom_types[b1]*7 + atom_types[b2];
            const float dd = d - bond_lengths[k];
            acc = 0.5 * (double)(bond_coeffs[k] * dd * dd);
        } else if (item < NB + NA) {
            const int ai = item - NB;
            const int a1 = angle_idx[ai*3+0];
            const int a2 = angle_idx[ai*3+1];
            const int a3 = angle_idx[ai*3+2];
            const float v1x = pos[a1*3+0] - pos[a2*3+0];
            const float v1y = pos[a1*3+1] - pos[a2*3+1];
            const float v1z = pos[a1*3+2] - pos[a2*3+2];
            const float v2x = pos[a3*3+0] - pos[a2*3+0];
            const float v2y = pos[a3*3+1] - pos[a2*3+1];
            const float v2z = pos[a3*3+2] - pos[a2*3+2];
            const float n1 = sqrtf(v1x*v1x + v1y*v1y + v1z*v1z + 1e-12f);
            const float n2 = sqrtf(v2x*v2x + v2y*v2y + v2z*v2z + 1e-12f);
            float cosa = (v1x*v2x + v1y*v2y + v1z*v2z) / (n1 * n2);
            cosa = fminf(fmaxf(cosa, -1.0f + 1e-7f), 1.0f - 1e-7f);
            const float ang = acosf(cosa);
            const int k = atom_types[a1]*49 + atom_types[a2]*7 + atom_types[a3];
            const float dt = ang - thetas[k];
            acc = 0.5 * (double)(angle_coeffs[k] * dt * dt);
        } else {
            const int di = item - NB - NA;
            const int q1 = dihedral_idx[di*4+0];
            const int q2 = dihedral_idx[di*4+1];
            const int q3 = dihedral_idx[di*4+2];
            const int q4 = dihedral_idx[di*4+3];
            const float w1x = pos[q2*3+0] - pos[q1*3+0];
            const float w1y = pos[q2*3+1] - pos[q1*3+1];
            const float w1z = pos[q2*3+2] - pos[q1*3+2];
            const float w2x = pos[q3*3+0] - pos[q2*3+0];
            const float w2y = pos[q3*3+1] - pos[q2*3+1];
            const float w2z = pos[q3*3+2] - pos[q2*3+2];
            const float w3x = pos[q4*3+0] - pos[q3*3+0];
            const float w3y = pos[q4*3+1] - pos[q3*3+1];
            const float w3z = pos[q4*3+2] - pos[q3*3+2];
            const float n1x = w1y*w2z - w1z*w2y;
            const float n1y = w1z*w2x - w1x*w2z;
            const float n1z = w1x*w2y - w1y*w2x;
            const float n2x = w2y*w3z - w2z*w3y;
            const float n2y = w2z*w3x - w2x*w3z;
            const float n2z = w2x*w3y - w2y*w3x;
            const float nn1 = sqrtf(n1x*n1x + n1y*n1y + n1z*n1z + 1e-12f);
            const float nn2 = sqrtf(n2x*n2x + n2y*n2y + n2z*n2z + 1e-12f);
            const float nw2 = sqrtf(w2x*w2x + w2y*w2y + w2z*w2z + 1e-12f);
            const float cosd = (n1x*n2x + n1y*n2y + n1z*n2z) / (nn1 * nn2);
            const float cx = n1y*n2z - n1z*n2y;
            const float cy = n1z*n2x - n1x*n2z;
            const float cz = n1x*n2y - n1y*n2x;
            const float sind = (cx*w2x + cy*w2y + cz*w2z) / (nw2 * nn1 * nn2);
            const float phi = atan2f(sind, cosd);
            const int k = atom_types[q2]*7 + atom_types[q3];
            const float e = 0.5f * dihedral_coeffs[k]
                          * (1.0f + cosf(multiplicity[k]*phi - phis[k]));
            acc = (double)e;
        }
    }

    // ---------------- block reduction -> one atomic per block ----------------
    #pragma unroll
    for (int s = 32; s > 0; s >>= 1) acc += __shfl_down(acc, s, 64);
    if ((tid & 63) == 0) red[tid >> 6] = acc;
    __syncthreads();
    if (tid == 0) {
        const float tot = (float)(red[0] + red[1] + red[2] + red[3]);
        atomicAdd(out, tot);
    }
}

extern "C" void kernel_launch(void* const* d_in, const int* in_sizes, int n_in,
                              void* d_out, int out_size, void* d_ws, size_t ws_size,
                              hipStream_t stream) {
    (void)in_sizes; (void)n_in; (void)d_ws; (void)ws_size; (void)out_size;
    hipMemsetAsync(d_out, 0, sizeof(float), stream);
    dim3 grid(NTILES, NTILES);   // upper-tri = pair tiles, lower-tri = bonded
    energy_kernel<<<grid, 256, 0, stream>>>(
        (const float*)d_in[0],  (const float*)d_in[1],
        (const float*)d_in[2],  (const float*)d_in[3],
        (const float*)d_in[4],  (const float*)d_in[5],
        (const float*)d_in[6],  (const float*)d_in[7],
        (const float*)d_in[8],  (const float*)d_in[9],
        (const float*)d_in[10], (const int*)d_in[11],
        (const int*)d_in[12],   (const int*)d_in[13],
        (const int*)d_in[14],   (const int*)d_in[15],
        (float*)d_out);
}

// Round 3
// 102.467 us; speedup vs baseline: 1.0211x; 1.0211x over previous
//
#include <hip/hip_runtime.h>

#define NATOMS 4096
#define TILE   128
#define NTILES (NATOMS / TILE)   // 32
#define KE2F   0.000231f

// Pairs with direct-formula d2 < NEAR_D2 (~2-6 pairs globally) get the bitwise
// np-f32 replication (cancellation noise there is amplified by r^-12 into the
// 1e20+ range). Everything else: fast f32 path, deviation <= ~1e15 total.
#define NEAR_D2 4e-3f

__global__ __launch_bounds__(256) void energy_kernel(
    const float* __restrict__ pos,
    const float* __restrict__ charges,
    const float* __restrict__ bond_coeffs,
    const float* __restrict__ bond_lengths,
    const float* __restrict__ angle_coeffs,
    const float* __restrict__ thetas,
    const float* __restrict__ dihedral_coeffs,
    const float* __restrict__ phis,
    const float* __restrict__ multiplicity,
    const float* __restrict__ lj_E,
    const float* __restrict__ lj_r,
    const int* __restrict__ atom_types,
    const int* __restrict__ lj_types,
    const int* __restrict__ bond_idx,
    const int* __restrict__ angle_idx,
    const int* __restrict__ dihedral_idx,
    float* __restrict__ out)
{
    const int bi  = blockIdx.y;
    const int bj  = blockIdx.x;
    const int tid = threadIdx.x;

    __shared__ float4 sp[TILE];   // x, y, z, charge of j-tile
    __shared__ int    st[TILE];   // lj type of j
    __shared__ double red[4];

    double acc = 0.0;   // near-pair (np-replicated) contributions, f64

    if (bj >= bi) {
        // ---------------- pairwise LJ + Coulomb tile ----------------
        const int il  = tid & (TILE - 1);
        const int sub = tid >> 7;            // 2 threads per i-row, 64 j's each
        const int ig  = bi * TILE + il;
        const int jb  = bj * TILE;

        if (tid < TILE) {
            const int jg = jb + tid;
            sp[tid] = make_float4(pos[jg*3+0], pos[jg*3+1], pos[jg*3+2], charges[jg]);
            st[tid] = lj_types[jg];
        }

        const float xi = pos[ig*3+0], yi = pos[ig*3+1], zi = pos[ig*3+2];
        // np-convention squared norm of i (only consumed by the rare slow path)
        const float sqi = __fadd_rn(__fadd_rn(__fmul_rn(xi,xi), __fmul_rn(yi,yi)),
                                    __fmul_rn(zi,zi));
        const float aqi = __fmul_rn(KE2F, charges[ig]);
        const int   ti  = lj_types[ig];
        const float e0 = 4.f*lj_E[ti*4+0], e1 = 4.f*lj_E[ti*4+1],
                    e2 = 4.f*lj_E[ti*4+2], e3 = 4.f*lj_E[ti*4+3];
        const float s0 = lj_r[ti*4+0], s1 = lj_r[ti*4+1],
                    s2 = lj_r[ti*4+2], s3 = lj_r[ti*4+3];
        // diagonal blocks need jj > il; off-diagonal blocks: all j valid
        const int jmin = (bi == bj) ? il : -1;

        __syncthreads();

        float accf = 0.0f;   // far-pair contributions, f32 (terms <= ~10 each)
        const int j0 = sub * (TILE/2);
        #pragma unroll 8
        for (int jj = j0; jj < j0 + TILE/2; ++jj) {
            const float4 pj = sp[jj];        // wave-uniform LDS broadcast
            const int    tj = st[jj];

            const float dx = xi - pj.x;
            const float dy = yi - pj.y;
            const float dz = zi - pj.z;
            const float d2 = __fmaf_rn(dx,dx, __fmaf_rn(dy,dy, dz*dz)); // >= 0

            const float sig = (tj==0)?s0:(tj==1)?s1:(tj==2)?s2:s3;
            const float e4  = (tj==0)?e0:(tj==1)?e1:(tj==2)?e2:e3;
            const bool valid = jj > jmin;

            if (__builtin_expect(d2 < NEAR_D2, 0)) {
                // ~2-6 pairs in the whole system: replicate np f32 bitwise
                if (valid) {
                    const float sqj = __fadd_rn(__fadd_rn(__fmul_rn(pj.x,pj.x),
                                                          __fmul_rn(pj.y,pj.y)),
                                                __fmul_rn(pj.z,pj.z));
                    const float dot = __fmaf_rn(zi, pj.z,
                                      __fmaf_rn(yi, pj.y,
                                      __fmaf_rn(xi, pj.x, 0.0f)));
                    const float t   = __fadd_rn(sqi, sqj);
                    const float d2n = __fsub_rn(t, __fmul_rn(2.0f, dot));
                    const float rr2 = __fadd_rn(fmaxf(d2n, 0.0f), 1e-12f);
                    const float rf  = __fsqrt_rn(rr2);
                    const float qv  = __fdiv_rn(sig, rf);
                    const double u  = (double)qv;
                    const double u3 = u*u*u;
                    const float r6  = (float)(u3*u3);      // ~correctly-rounded q**6
                    const float lj  = __fsub_rn(__fmul_rn(r6, r6), r6);
                    acc += (double)__fmul_rn(e4, lj);
                    acc += (double)__fdiv_rn(__fmul_rn(aqi, pj.w), rf);
                }
            } else {
                const float invr = __builtin_amdgcn_rsqf(d2 + 1e-12f);
                const float u  = sig * invr;
                const float u2 = u*u;
                const float u6 = u2*u2*u2;
                const float term = e4 * (u6*u6 - u6) + (aqi * pj.w) * invr;
                accf += valid ? term : 0.0f;
            }
        }
        acc += (double)accf;
    } else {
        // ---------------- bonded terms on spare lower-tri blocks ----------------
        const int l   = (bi * (bi - 1)) / 2 + bj;   // 0..495
        const int NB  = NATOMS;                     // 4096 bonds
        const int NA  = 2 * NATOMS;                 // 8192 angles
        const int ND  = 3 * NATOMS;                 // 12288 dihedrals
        const int TOT = NB + NA + ND;               // 24576 = 96 blocks exactly
        if (l * 256 >= TOT) return;                 // whole block idle (uniform)
        const int item = l * 256 + tid;

        if (item < NB) {
            const int b1 = bond_idx[item*2+0];
            const int b2 = bond_idx[item*2+1];
            const float dx = pos[b1*3+0] - pos[b2*3+0];
            const float dy = pos[b1*3+1] - pos[b2*3+1];
            const float dz = pos[b1*3+2] - pos[b2*3+2];
            const float d  = sqrtf(dx*dx + dy*dy + dz*dz + 1e-12f);
            const int k    = atom_types[b1]*7 + atom_types[b2];
            const float dd = d - bond_lengths[k];
            acc = 0.5 * (double)(bond_coeffs[k] * dd * dd);
        } else if (item < NB + NA) {
            const int ai = item - NB;
            const int a1 = angle_idx[ai*3+0];
            const int a2 = angle_idx[ai*3+1];
            const int a3 = angle_idx[ai*3+2];
            const float v1x = pos[a1*3+0] - pos[a2*3+0];
            const float v1y = pos[a1*3+1] - pos[a2*3+1];
            const float v1z = pos[a1*3+2] - pos[a2*3+2];
            const float v2x = pos[a3*3+0] - pos[a2*3+0];
            const float v2y = pos[a3*3+1] - pos[a2*3+1];
            const float v2z = pos[a3*3+2] - pos[a2*3+2];
            const float n1 = sqrtf(v1x*v1x + v1y*v1y + v1z*v1z + 1e-12f);
            const float n2 = sqrtf(v2x*v2x + v2y*v2y + v2z*v2z + 1e-12f);
            float cosa = (v1x*v2x + v1y*v2y + v1z*v2z) / (n1 * n2);
            cosa = fminf(fmaxf(cosa, -1.0f + 1e-7f), 1.0f - 1e-7f);
            const float ang = acosf(cosa);
            const int k = atom_types[a1]*49 + atom_types[a2]*7 + atom_types[a3];
            const float dt = ang - thetas[k];
            acc = 0.5 * (double)(angle_coeffs[k] * dt * dt);
        } else {
            const int di = item - NB - NA;
            const int q1 = dihedral_idx[di*4+0];
            const int q2 = dihedral_idx[di*4+1];
            const int q3 = dihedral_idx[di*4+2];
            const int q4 = dihedral_idx[di*4+3];
            const float w1x = pos[q2*3+0] - pos[q1*3+0];
            const float w1y = pos[q2*3+1] - pos[q1*3+1];
            const float w1z = pos[q2*3+2] - pos[q1*3+2];
            const float w2x = pos[q3*3+0] - pos[q2*3+0];
            const float w2y = pos[q3*3+1] - pos[q2*3+1];
            const float w2z = pos[q3*3+2] - pos[q2*3+2];
            const float w3x = pos[q4*3+0] - pos[q3*3+0];
            const float w3y = pos[q4*3+1] - pos[q3*3+1];
            const float w3z = pos[q4*3+2] - pos[q3*3+2];
            const float n1x = w1y*w2z - w1z*w2y;
            const float n1y = w1z*w2x - w1x*w2z;
            const float n1z = w1x*w2y - w1y*w2x;
            const float n2x = w2y*w3z - w2z*w3y;
            const float n2y = w2z*w3x - w2x*w3z;
            const float n2z = w2x*w3y - w2y*w3x;
            const float nn1 = sqrtf(n1x*n1x + n1y*n1y + n1z*n1z + 1e-12f);
            const float nn2 = sqrtf(n2x*n2x + n2y*n2y + n2z*n2z + 1e-12f);
            const float nw2 = sqrtf(w2x*w2x + w2y*w2y + w2z*w2z + 1e-12f);
            const float cosd = (n1x*n2x + n1y*n2y + n1z*n2z) / (nn1 * nn2);
            const float cx = n1y*n2z - n1z*n2y;
            const float cy = n1z*n2x - n1x*n2z;
            const float cz = n1x*n2y - n1y*n2x;
            const float sind = (cx*w2x + cy*w2y + cz*w2z) / (nw2 * nn1 * nn2);
            const float phi = atan2f(sind, cosd);
            const int k = atom_types[q2]*7 + atom_types[q3];
            const float e = 0.5f * dihedral_coeffs[k]
                          * (1.0f + cosf(multiplicity[k]*phi - phis[k]));
            acc = (double)e;
        }
    }

    // ---------------- block reduction -> one atomic per block ----------------
    #pragma unroll
    for (int s = 32; s > 0; s >>= 1) acc += __shfl_down(acc, s, 64);
    if ((tid & 63) == 0) red[tid >> 6] = acc;
    __syncthreads();
    if (tid == 0) {
        const float tot = (float)(red[0] + red[1] + red[2] + red[3]);
        atomicAdd(out, tot);
    }
}

extern "C" void kernel_launch(void* const* d_in, const int* in_sizes, int n_in,
                              void* d_out, int out_size, void* d_ws, size_t ws_size,
                              hipStream_t stream) {
    (void)in_sizes; (void)n_in; (void)d_ws; (void)ws_size; (void)out_size;
    hipMemsetAsync(d_out, 0, sizeof(float), stream);
    dim3 grid(NTILES, NTILES);   // upper-tri = pair tiles, lower-tri = bonded
    energy_kernel<<<grid, 256, 0, stream>>>(
        (const float*)d_in[0],  (const float*)d_in[1],
        (const float*)d_in[2],  (const float*)d_in[3],
        (const float*)d_in[4],  (const float*)d_in[5],
        (const float*)d_in[6],  (const float*)d_in[7],
        (const float*)d_in[8],  (const float*)d_in[9],
        (const float*)d_in[10], (const int*)d_in[11],
        (const int*)d_in[12],   (const int*)d_in[13],
        (const int*)d_in[14],   (const int*)d_in[15],
        (float*)d_out);
}